// Round 15
// baseline (254.603 us; speedup 1.0000x reference)
//
#include <hip/hip_runtime.h>

typedef short bf16x8 __attribute__((ext_vector_type(8)));
typedef float f32x4 __attribute__((ext_vector_type(4)));
typedef unsigned int uint;
typedef unsigned short ushort;
typedef uint u32x2 __attribute__((ext_vector_type(2)));
typedef uint u32x4 __attribute__((ext_vector_type(4)));

#define NBLK 256   // edge-chunk blocks for pA
#define LCAP 24576 // p4 LDS edge buffer (96 KB)
#define HP 264     // H row stride in ushorts (528B, 16B-aligned)
#define BCAP 6144  // slab capacity per bucket (mean 4096; +32 sigma)

__device__ inline ushort f2bf(float f) {
    uint u = __builtin_bit_cast(uint, f);
    uint r = u + 0x7fffu + ((u >> 16) & 1u);  // round-to-nearest-even
    return (ushort)(r >> 16);
}
__device__ inline float bf2f(uint lo16) {
    uint u = lo16 << 16;
    return __builtin_bit_cast(float, u);
}
__device__ inline float bf2f_hi(uint v) {
    uint u = v & 0xffff0000u;
    return __builtin_bit_cast(float, u);
}

// ---------------- packw: fp32 W -> MFMA B-fragment order (ks-major), bf16 ----------------
__device__ inline void packw_body(const float* __restrict__ Wa, const float* __restrict__ Wb,
                                  ushort* __restrict__ out, int mode, int tile, int l) {
    int cb = tile >> 3, ks = tile & 7;
    int col = cb * 16 + (l & 15);
    int k0 = ks * 32 + ((l >> 4) * 8);
    ushort vals[8];
#pragma unroll
    for (int j = 0; j < 8; j++) {
        int k = k0 + j;
        float f;
        if (mode == 0)
            f = (k < 128) ? Wa[(size_t)k * 256 + col] : Wb[(size_t)(k - 128) * 256 + col];
        else
            f = (col < 128) ? Wa[(size_t)k * 128 + col] : Wb[(size_t)k * 128 + (col - 128)];
        vals[j] = f2bf(f);
    }
    ushort* dst = out + ((size_t)(ks * 16 + cb) * 64 + l) * 8;
#pragma unroll
    for (int j = 0; j < 8; j++) dst[j] = vals[j];
}

// ---------------- fused prep: pA (hist+reserve+scatter) + packw x2 + convx ----------------
__global__ void prep_kernel(const float* __restrict__ x, ushort* __restrict__ a1,
                            const float* __restrict__ Wr0, const float* __restrict__ Wl0,
                            ushort* __restrict__ w1p,
                            const float* __restrict__ Wl1, const float* __restrict__ Wr1,
                            ushort* __restrict__ w2p,
                            const int* __restrict__ srcv, const int* __restrict__ dstv,
                            int* __restrict__ bcnt, uint* __restrict__ slab,
                            int E, int CE, int NB, int n) {
    __shared__ int hist[512];
    __shared__ int base2[512];
    int bb = blockIdx.x;
    int tid = threadIdx.x;
    if (bb < NBLK) {
        for (int b = tid; b < NB; b += 256) hist[b] = 0;
        __syncthreads();
        int start = bb * CE, end = min(E, start + CE);
        for (int e = start + tid; e < end; e += 256)
            atomicAdd(&hist[dstv[e] >> 8], 1);
        __syncthreads();
        for (int b = tid; b < NB; b += 256) {
            int c = hist[b];
            base2[b] = (c > 0) ? atomicAdd(&bcnt[b], c) : 0;
            hist[b] = 0;  // reuse as local cursor
        }
        __syncthreads();
        for (int e = start + tid; e < end; e += 256) {
            int d = dstv[e];
            int s = srcv[e];
            int bkt = d >> 8;
            int off = atomicAdd(&hist[bkt], 1);
            int slot = base2[bkt] + off;
            if (slot < BCAP)
                slab[(size_t)bkt * BCAP + slot] = ((uint)(d & 255) << 17) | (uint)s;
        }
    } else if (bb < NBLK + 64) {
        int r = bb - NBLK;
        int tile = (r & 31) * 4 + (tid >> 6);
        int l = tid & 63;
        if (r < 32) packw_body(Wr0, Wl0, w1p, 0, tile, l);
        else        packw_body(Wl1, Wr1, w2p, 1, tile, l);
    } else {
        int i = (bb - NBLK - 64) * 256 + tid;
        int total = n * 32;
        if (i < total) {
            int row = i >> 5, q = i & 31;
            float4 v = *(const float4*)(x + (size_t)row * 128 + q * 4);
            ushort4 o;
            o.x = f2bf(v.x); o.y = f2bf(v.y); o.z = f2bf(v.z); o.w = f2bf(v.w);
            *(ushort4*)(a1 + (size_t)row * 256 + q * 4) = o;
        }
    }
}

// ---------------- p4: slab -> rs + nbr; absorbs bucket-count scan (pB) ----------------
__global__ void p4_kernel(const uint* __restrict__ slab, const int* __restrict__ bcnt,
                          int* __restrict__ rs, int* __restrict__ nbr, int n, int E, int NB) {
    __shared__ uint ebuf[LCAP];
    __shared__ int cnt[256];
    __shared__ int cur[256];
    __shared__ int red[256];
    int tid = threadIdx.x;
    int b = blockIdx.x;
    int d0 = b << 8;
    // eb = sum_{t<b} min(bcnt[t], BCAP)
    int s = 0;
    for (int t = tid; t < b; t += 256) s += min(bcnt[t], BCAP);
    red[tid] = s;
    __syncthreads();
#pragma unroll
    for (int off = 128; off > 0; off >>= 1) {
        if (tid < off) red[tid] += red[tid + off];
        __syncthreads();
    }
    int eb = red[0];
    int m = min(bcnt[b], BCAP);
    const uint* sl = slab + (size_t)b * BCAP;
    cnt[tid] = 0;
    __syncthreads();
    for (int i = tid; i < m; i += 256) {
        uint v = sl[i];
        if (i < LCAP) ebuf[i] = v;
        atomicAdd(&cnt[v >> 17], 1);
    }
    __syncthreads();
    int v0 = cnt[tid];
    cur[tid] = v0;
    __syncthreads();
#pragma unroll
    for (int off = 1; off < 256; off <<= 1) {
        int t = (tid >= off) ? cur[tid - off] : 0;
        __syncthreads();
        cur[tid] += t;
        __syncthreads();
    }
    int excl = cur[tid] - v0;
    int node = d0 + tid;
    if (node < n) rs[node] = eb + excl;
    if (b == NB - 1 && tid == 0) rs[n] = E;
    __syncthreads();
    cur[tid] = eb + excl;
    __syncthreads();
    for (int i = tid; i < m; i += 256) {
        uint v = (i < LCAP) ? ebuf[i] : sl[i];
        int p = atomicAdd(&cur[v >> 17], 1);
        nbr[p] = (int)(v & 0x1FFFFu);
    }
}

// ---------------- fused 2-layer MFMA GEMM: 16 waves, 1 col-block (16 cols) per wave ----------
// Block = 128 rows, 1024 threads. Wave w owns cols [16w, 16w+16) for ALL 128 rows of both
// layers; B-frags 32 VGPRs/layer (bf1 dead before bf2 lives) -> ~4 waves/SIMD occupancy.
// LDS H[128][HP]: A1 tile, then h (wave-private column slices). All transitions fenced.
__launch_bounds__(1024, 1)
__global__ void fused_gemm_kernel(const ushort* __restrict__ A, const ushort* __restrict__ W1,
                                  const ushort* __restrict__ W2, const float* __restrict__ b0,
                                  const float* __restrict__ b1, ushort* __restrict__ zb,
                                  ushort* __restrict__ sb, int n) {
    extern __shared__ ushort H[];  // [128][HP]
    int tid = threadIdx.x;
    int l = tid & 63, w = tid >> 6;  // 16 waves
    int q = l >> 4, r16 = l & 15;
    int row0 = blockIdx.x * 128;

    // ---- stage A1 tile -> H (cooperative; 32 lanes = one 512B row) ----
    {
        int rr = tid >> 5;          // 0..31
        int cc = (tid & 31) * 8;
#pragma unroll
        for (int it = 0; it < 4; it++) {
            int lr = it * 32 + rr;
            int row = row0 + lr;
            if (row > n - 1) row = n - 1;
            u32x4 v = *(const u32x4*)(A + (size_t)row * 256 + cc);
            *(u32x4*)(&H[(size_t)lr * HP + cc]) = v;
        }
    }

    // ---- layer-1 B fragments: cb = w ----
    bf16x8 bf1[8];
#pragma unroll
    for (int ks = 0; ks < 8; ks++)
        bf1[ks] = *(const bf16x8*)(W1 + ((size_t)((ks * 16 + w) * 64 + l)) * 8);

    f32x4 acc[8];
#pragma unroll
    for (int rg = 0; rg < 8; rg++) acc[rg] = (f32x4){0.f, 0.f, 0.f, 0.f};

    __syncthreads();  // A1 tile staged

    // ================= layer 1 =================
#pragma unroll
    for (int rg = 0; rg < 8; rg++) {
        bf16x8 a[8];
        const ushort* hp = &H[(size_t)(rg * 16 + r16) * HP + q * 8];
#pragma unroll
        for (int ks = 0; ks < 8; ks++) a[ks] = *(const bf16x8*)(hp + ks * 32);
#pragma unroll
        for (int ks = 0; ks < 8; ks++)
            acc[rg] = __builtin_amdgcn_mfma_f32_16x16x32_bf16(bf1[ks], a[ks], acc[rg], 0, 0, 0);
    }

    // prefetch layer-2 B frags (L2 latency hides under barrier + epilogue-1)
    bf16x8 bf2[8];
#pragma unroll
    for (int ks = 0; ks < 8; ks++)
        bf2[ks] = *(const bf16x8*)(W2 + ((size_t)((ks * 16 + w) * 64 + l)) * 8);

    __syncthreads();  // all A1 reads done; safe to overwrite H with h

    // ---- epilogue 1: h = relu(acc + b0) -> H column slice [16w, 16w+16) ----
    {
        int colb = w * 16 + q * 4;
        f32x4 bv = *(const f32x4*)(b0 + colb);
#pragma unroll
        for (int rg = 0; rg < 8; rg++) {
            f32x4 v = acc[rg];
            float v0 = fmaxf(v[0] + bv[0], 0.f);
            float v1 = fmaxf(v[1] + bv[1], 0.f);
            float v2 = fmaxf(v[2] + bv[2], 0.f);
            float v3 = fmaxf(v[3] + bv[3], 0.f);
            u32x2 pk;
            pk[0] = (uint)f2bf(v0) | ((uint)f2bf(v1) << 16);
            pk[1] = (uint)f2bf(v2) | ((uint)f2bf(v3) << 16);
            *(u32x2*)(&H[(size_t)(rg * 16 + r16) * HP + colb]) = pk;
            acc[rg] = (f32x4){0.f, 0.f, 0.f, 0.f};
        }
    }

    __syncthreads();  // h complete

    // ================= layer 2 =================
#pragma unroll
    for (int rg = 0; rg < 8; rg++) {
        bf16x8 a[8];
        const ushort* hp = &H[(size_t)(rg * 16 + r16) * HP + q * 8];
#pragma unroll
        for (int ks = 0; ks < 8; ks++) a[ks] = *(const bf16x8*)(hp + ks * 32);
#pragma unroll
        for (int ks = 0; ks < 8; ks++)
            acc[rg] = __builtin_amdgcn_mfma_f32_16x16x32_bf16(bf2[ks], a[ks], acc[rg], 0, 0, 0);
    }

    // ---- epilogue 2: DIRECT global stores (bf16 both halves) ----
    if (w < 8) {
        int colb = w * 16 + q * 4;
#pragma unroll
        for (int rg = 0; rg < 8; rg++) {
            int row = row0 + rg * 16 + r16;
            f32x4 v = acc[rg];
            u32x2 pk;
            pk[0] = (uint)f2bf(v[0]) | ((uint)f2bf(v[1]) << 16);
            pk[1] = (uint)f2bf(v[2]) | ((uint)f2bf(v[3]) << 16);
            if (row < n)
                *(u32x2*)(zb + (size_t)row * 128 + colb) = pk;
        }
    } else {
        int colb = (w - 8) * 16 + q * 4;
        f32x4 bv = *(const f32x4*)(b1 + colb);
#pragma unroll
        for (int rg = 0; rg < 8; rg++) {
            int row = row0 + rg * 16 + r16;
            f32x4 v = acc[rg];
            v[0] += bv[0]; v[1] += bv[1]; v[2] += bv[2]; v[3] += bv[3];
            u32x2 pk;
            pk[0] = (uint)f2bf(v[0]) | ((uint)f2bf(v[1]) << 16);
            pk[1] = (uint)f2bf(v[2]) | ((uint)f2bf(v[3]) << 16);
            if (row < n)
                *(u32x2*)(sb + (size_t)row * 128 + colb) = pk;
        }
    }
}

// ---------------- segment mean v4 (R14-validated): uint4 gathers, 16 rows in flight ----------
template <int ADD>
__global__ void segmean_kernel(const u32x4* __restrict__ fp, int rstride,
                               const int* __restrict__ rs, const int* __restrict__ nbr,
                               u32x4* __restrict__ outb, int ostride,
                               float* __restrict__ outf, const ushort* __restrict__ sb, int n) {
    int w = threadIdx.x >> 6;
    int l = threadIdx.x & 63;
    int i = blockIdx.x * 4 + w;
    if (i >= n) return;
    int g = l >> 4, f = l & 15;
    int b = rs[i], e = rs[i + 1];
    float a0 = 0.f, a1 = 0.f, a2 = 0.f, a3 = 0.f, a4 = 0.f, a5 = 0.f, a6 = 0.f, a7 = 0.f;
    auto accum = [&](u32x4 v) {
        a0 += bf2f(v[0] & 0xffffu); a1 += bf2f_hi(v[0]);
        a2 += bf2f(v[1] & 0xffffu); a3 += bf2f_hi(v[1]);
        a4 += bf2f(v[2] & 0xffffu); a5 += bf2f_hi(v[2]);
        a6 += bf2f(v[3] & 0xffffu); a7 += bf2f_hi(v[3]);
    };
    int j = b;
    for (; j + 16 <= e; j += 16) {
        int s0 = nbr[j + g], s1 = nbr[j + 4 + g], s2 = nbr[j + 8 + g], s3 = nbr[j + 12 + g];
        u32x4 v0 = fp[(size_t)s0 * rstride + f];
        u32x4 v1 = fp[(size_t)s1 * rstride + f];
        u32x4 v2 = fp[(size_t)s2 * rstride + f];
        u32x4 v3 = fp[(size_t)s3 * rstride + f];
        accum(v0); accum(v1); accum(v2); accum(v3);
    }
    for (; j + 4 <= e; j += 4) {
        u32x4 v = fp[(size_t)nbr[j + g] * rstride + f];
        accum(v);
    }
    int rem = e - j;
    if (g < rem) {
        u32x4 v = fp[(size_t)nbr[j + g] * rstride + f];
        accum(v);
    }
    a0 += __shfl_xor(a0, 32); a0 += __shfl_xor(a0, 16);
    a1 += __shfl_xor(a1, 32); a1 += __shfl_xor(a1, 16);
    a2 += __shfl_xor(a2, 32); a2 += __shfl_xor(a2, 16);
    a3 += __shfl_xor(a3, 32); a3 += __shfl_xor(a3, 16);
    a4 += __shfl_xor(a4, 32); a4 += __shfl_xor(a4, 16);
    a5 += __shfl_xor(a5, 32); a5 += __shfl_xor(a5, 16);
    a6 += __shfl_xor(a6, 32); a6 += __shfl_xor(a6, 16);
    a7 += __shfl_xor(a7, 32); a7 += __shfl_xor(a7, 16);
    if (g == 0) {
        int dg = e - b;
        float inv = 1.0f / (float)(dg > 1 ? dg : 1);
        a0 *= inv; a1 *= inv; a2 *= inv; a3 *= inv;
        a4 *= inv; a5 *= inv; a6 *= inv; a7 *= inv;
        if (ADD) {
            u32x4 sv = *(const u32x4*)(sb + (size_t)i * 128 + f * 8);
            f32x4 o0, o1;
            o0[0] = bf2f(sv[0] & 0xffffu) + a0; o0[1] = bf2f_hi(sv[0]) + a1;
            o0[2] = bf2f(sv[1] & 0xffffu) + a2; o0[3] = bf2f_hi(sv[1]) + a3;
            o1[0] = bf2f(sv[2] & 0xffffu) + a4; o1[1] = bf2f_hi(sv[2]) + a5;
            o1[2] = bf2f(sv[3] & 0xffffu) + a6; o1[3] = bf2f_hi(sv[3]) + a7;
            float* op = outf + (size_t)i * 128 + f * 8;
            *(f32x4*)op = o0;
            *(f32x4*)(op + 4) = o1;
        } else {
            u32x4 pk;
            pk[0] = (uint)f2bf(a0) | ((uint)f2bf(a1) << 16);
            pk[1] = (uint)f2bf(a2) | ((uint)f2bf(a3) << 16);
            pk[2] = (uint)f2bf(a4) | ((uint)f2bf(a5) << 16);
            pk[3] = (uint)f2bf(a6) | ((uint)f2bf(a7) << 16);
            outb[(size_t)i * ostride + f] = pk;
        }
    }
}

// ---------------- launch ----------------

extern "C" void kernel_launch(void* const* d_in, const int* in_sizes, int n_in,
                              void* d_out, int out_size, void* d_ws, size_t ws_size,
                              hipStream_t stream) {
    const float* x = (const float*)d_in[0];
    const int* ei = (const int*)d_in[1];
    const float* Wl0 = (const float*)d_in[2];
    const float* bl0 = (const float*)d_in[3];
    const float* Wr0 = (const float*)d_in[4];
    const float* Wl1 = (const float*)d_in[5];
    const float* bl1 = (const float*)d_in[6];
    const float* Wr1 = (const float*)d_in[7];
    float* outp = (float*)d_out;

    int n = in_sizes[0] / 128;  // 100000
    int E = in_sizes[1] / 2;    // 1600000
    const int* srcv = ei;
    const int* dstv = ei + E;

    int NB = (n + 255) >> 8;        // 391
    int CE = (E + NBLK - 1) / NBLK; // edges per pA block

    char* w = (char*)d_ws;
    auto align = [](size_t v) { return (v + 255) & ~(size_t)255; };
    size_t off = 0;
    int* rs    = (int*)(w + off); off = align(off + (size_t)(n + 1) * 4);
    int* bcnt  = (int*)(w + off); off = align(off + (size_t)512 * 4);
    int* nbr   = (int*)(w + off); off = align(off + (size_t)E * 4);
    ushort* a1  = (ushort*)(w + off); off = align(off + (size_t)n * 256 * 2);  // [xb | aggb]
    ushort* zb  = (ushort*)(w + off); off = align(off + (size_t)n * 128 * 2);
    ushort* sbf = (ushort*)(w + off); off = align(off + (size_t)n * 128 * 2);  // bf16 self-term
    ushort* w1p = (ushort*)(w + off); off = align(off + (size_t)256 * 256 * 2);
    ushort* w2p = (ushort*)(w + off); off = align(off + (size_t)256 * 256 * 2);
    uint* slab = (uint*)zb;  // slab (9.6 MB) aliases zb (25.6 MB): dead before fused writes zb
    (void)ws_size; (void)n_in; (void)out_size;

    int ncx = (n * 32 + 255) / 256;

    hipMemsetAsync(bcnt, 0, (size_t)512 * 4, stream);

    // CSR build (single edge pass) + conversions
    prep_kernel<<<NBLK + 64 + ncx, 256, 0, stream>>>(x, a1, Wr0, Wl0, w1p, Wl1, Wr1, w2p,
                                                     srcv, dstv, bcnt, slab, E, CE, NB, n);
    p4_kernel<<<NB, 256, 0, stream>>>(slab, bcnt, rs, nbr, n, E, NB);

    int segb = (n + 3) / 4;
    int mb = (n + 127) / 128;
    int ldsz = 128 * HP * 2;  // 67584

    hipFuncSetAttribute((const void*)fused_gemm_kernel,
                        hipFuncAttributeMaxDynamicSharedMemorySize, ldsz);

    // layer 1 gather, fused 2-layer GEMM, layer 2 gather + self-term combine
    segmean_kernel<0><<<segb, 256, 0, stream>>>((const u32x4*)a1, 32, rs, nbr,
                                                (u32x4*)a1 + 16, 32, nullptr, nullptr, n);
    fused_gemm_kernel<<<mb, 1024, ldsz, stream>>>(a1, w1p, w2p, bl0, bl1, zb, sbf, n);
    segmean_kernel<1><<<segb, 256, 0, stream>>>((const u32x4*)zb, 16, rs, nbr,
                                                nullptr, 0, outp, sbf, n);
}

// Round 16
// 241.560 us; speedup vs baseline: 1.0540x; 1.0540x over previous
//
#include <hip/hip_runtime.h>

typedef short bf16x8 __attribute__((ext_vector_type(8)));
typedef float f32x4 __attribute__((ext_vector_type(4)));
typedef unsigned int uint;
typedef unsigned short ushort;
typedef uint u32x2 __attribute__((ext_vector_type(2)));
typedef uint u32x4 __attribute__((ext_vector_type(4)));

#define NBLK 256   // edge-chunk blocks for pA
#define LCAP 24576 // p4 LDS edge buffer (96 KB)
#define HP 264     // H row stride in ushorts (528B, 16B-aligned)
#define BCAP 6144  // slab capacity per bucket (mean 4096; +32 sigma)

__device__ inline ushort f2bf(float f) {
    uint u = __builtin_bit_cast(uint, f);
    uint r = u + 0x7fffu + ((u >> 16) & 1u);  // round-to-nearest-even
    return (ushort)(r >> 16);
}
__device__ inline float bf2f(uint lo16) {
    uint u = lo16 << 16;
    return __builtin_bit_cast(float, u);
}
__device__ inline float bf2f_hi(uint v) {
    uint u = v & 0xffff0000u;
    return __builtin_bit_cast(float, u);
}

// ---------------- packw: fp32 W -> MFMA B-fragment order (ks-major), bf16 ----------------
__device__ inline void packw_body(const float* __restrict__ Wa, const float* __restrict__ Wb,
                                  ushort* __restrict__ out, int mode, int tile, int l) {
    int cb = tile >> 3, ks = tile & 7;
    int col = cb * 16 + (l & 15);
    int k0 = ks * 32 + ((l >> 4) * 8);
    ushort vals[8];
#pragma unroll
    for (int j = 0; j < 8; j++) {
        int k = k0 + j;
        float f;
        if (mode == 0)
            f = (k < 128) ? Wa[(size_t)k * 256 + col] : Wb[(size_t)(k - 128) * 256 + col];
        else
            f = (col < 128) ? Wa[(size_t)k * 128 + col] : Wb[(size_t)k * 128 + (col - 128)];
        vals[j] = f2bf(f);
    }
    ushort* dst = out + ((size_t)(ks * 16 + cb) * 64 + l) * 8;
#pragma unroll
    for (int j = 0; j < 8; j++) dst[j] = vals[j];
}

// ---------------- fused prep: pA (hist+reserve+scatter) + packw x2 + convx ----------------
__global__ void prep_kernel(const float* __restrict__ x, ushort* __restrict__ a1,
                            const float* __restrict__ Wr0, const float* __restrict__ Wl0,
                            ushort* __restrict__ w1p,
                            const float* __restrict__ Wl1, const float* __restrict__ Wr1,
                            ushort* __restrict__ w2p,
                            const int* __restrict__ srcv, const int* __restrict__ dstv,
                            int* __restrict__ bcnt, uint* __restrict__ slab,
                            int E, int CE, int NB, int n) {
    __shared__ int hist[512];
    __shared__ int base2[512];
    int bb = blockIdx.x;
    int tid = threadIdx.x;
    if (bb < NBLK) {
        for (int b = tid; b < NB; b += 256) hist[b] = 0;
        __syncthreads();
        int start = bb * CE, end = min(E, start + CE);
        for (int e = start + tid; e < end; e += 256)
            atomicAdd(&hist[dstv[e] >> 8], 1);
        __syncthreads();
        for (int b = tid; b < NB; b += 256) {
            int c = hist[b];
            base2[b] = (c > 0) ? atomicAdd(&bcnt[b], c) : 0;
            hist[b] = 0;  // reuse as local cursor
        }
        __syncthreads();
        for (int e = start + tid; e < end; e += 256) {
            int d = dstv[e];
            int s = srcv[e];
            int bkt = d >> 8;
            int off = atomicAdd(&hist[bkt], 1);
            int slot = base2[bkt] + off;
            if (slot < BCAP)
                slab[(size_t)bkt * BCAP + slot] = ((uint)(d & 255) << 17) | (uint)s;
        }
    } else if (bb < NBLK + 64) {
        int r = bb - NBLK;
        int tile = (r & 31) * 4 + (tid >> 6);
        int l = tid & 63;
        if (r < 32) packw_body(Wr0, Wl0, w1p, 0, tile, l);
        else        packw_body(Wl1, Wr1, w2p, 1, tile, l);
    } else {
        int i = (bb - NBLK - 64) * 256 + tid;
        int total = n * 32;
        if (i < total) {
            int row = i >> 5, q = i & 31;
            float4 v = *(const float4*)(x + (size_t)row * 128 + q * 4);
            ushort4 o;
            o.x = f2bf(v.x); o.y = f2bf(v.y); o.z = f2bf(v.z); o.w = f2bf(v.w);
            *(ushort4*)(a1 + (size_t)row * 256 + q * 4) = o;
        }
    }
}

// ---------------- p4: slab -> rs + nbr; absorbs bucket-count scan ----------------
__global__ void p4_kernel(const uint* __restrict__ slab, const int* __restrict__ bcnt,
                          int* __restrict__ rs, int* __restrict__ nbr, int n, int E, int NB) {
    __shared__ uint ebuf[LCAP];
    __shared__ int cnt[256];
    __shared__ int cur[256];
    __shared__ int red[256];
    int tid = threadIdx.x;
    int b = blockIdx.x;
    int d0 = b << 8;
    int s = 0;
    for (int t = tid; t < b; t += 256) s += min(bcnt[t], BCAP);
    red[tid] = s;
    __syncthreads();
#pragma unroll
    for (int off = 128; off > 0; off >>= 1) {
        if (tid < off) red[tid] += red[tid + off];
        __syncthreads();
    }
    int eb = red[0];
    int m = min(bcnt[b], BCAP);
    const uint* sl = slab + (size_t)b * BCAP;
    cnt[tid] = 0;
    __syncthreads();
    for (int i = tid; i < m; i += 256) {
        uint v = sl[i];
        if (i < LCAP) ebuf[i] = v;
        atomicAdd(&cnt[v >> 17], 1);
    }
    __syncthreads();
    int v0 = cnt[tid];
    cur[tid] = v0;
    __syncthreads();
#pragma unroll
    for (int off = 1; off < 256; off <<= 1) {
        int t = (tid >= off) ? cur[tid - off] : 0;
        __syncthreads();
        cur[tid] += t;
        __syncthreads();
    }
    int excl = cur[tid] - v0;
    int node = d0 + tid;
    if (node < n) rs[node] = eb + excl;
    if (b == NB - 1 && tid == 0) rs[n] = E;
    __syncthreads();
    cur[tid] = eb + excl;
    __syncthreads();
    for (int i = tid; i < m; i += 256) {
        uint v = (i < LCAP) ? ebuf[i] : sl[i];
        int p = atomicAdd(&cur[v >> 17], 1);
        nbr[p] = (int)(v & 0x1FFFFu);
    }
}

// ---------------- fused 2-layer MFMA GEMM: BM=64, 8 waves, 2 cb/wave (R13 structure) -------
// Block = 64 rows, 512 threads. Wave w owns cols [32w, 32w+32) for all 64 rows of both
// layers; B-frags in VGPRs. LDS H[64][HP] = 33.8 KB -> 3-4 blocks/CU resident.
__launch_bounds__(512, 1)
__global__ void fused_gemm_kernel(const ushort* __restrict__ A, const ushort* __restrict__ W1,
                                  const ushort* __restrict__ W2, const float* __restrict__ b0,
                                  const float* __restrict__ b1, ushort* __restrict__ zb,
                                  ushort* __restrict__ sb, int n) {
    extern __shared__ ushort H[];  // [64][HP]
    int tid = threadIdx.x;
    int l = tid & 63, w = tid >> 6;  // 8 waves
    int q = l >> 4, r16 = l & 15;
    int row0 = blockIdx.x * 64;

    // ---- stage A1 tile (64 rows) -> H ----
    {
        int rr = tid >> 5;          // 0..15
        int cc = (tid & 31) * 8;
#pragma unroll
        for (int it = 0; it < 4; it++) {
            int lr = it * 16 + rr;
            int row = row0 + lr;
            if (row > n - 1) row = n - 1;
            u32x4 v = *(const u32x4*)(A + (size_t)row * 256 + cc);
            *(u32x4*)(&H[(size_t)lr * HP + cc]) = v;
        }
    }

    // ---- layer-1 B fragments for this wave's cb pair ----
    bf16x8 bf1[2][8];
#pragma unroll
    for (int cbi = 0; cbi < 2; cbi++) {
        int cb = 2 * w + cbi;
#pragma unroll
        for (int ks = 0; ks < 8; ks++)
            bf1[cbi][ks] = *(const bf16x8*)(W1 + ((size_t)((ks * 16 + cb) * 64 + l)) * 8);
    }

    f32x4 acc[4][2];
#pragma unroll
    for (int rg = 0; rg < 4; rg++)
#pragma unroll
        for (int cbi = 0; cbi < 2; cbi++) acc[rg][cbi] = (f32x4){0.f, 0.f, 0.f, 0.f};

    __syncthreads();  // A1 tile staged

    // ================= layer 1 =================
#pragma unroll
    for (int rg = 0; rg < 4; rg++) {
        bf16x8 a[8];
        const ushort* hp = &H[(size_t)(rg * 16 + r16) * HP + q * 8];
#pragma unroll
        for (int ks = 0; ks < 8; ks++) a[ks] = *(const bf16x8*)(hp + ks * 32);
#pragma unroll
        for (int cbi = 0; cbi < 2; cbi++)
#pragma unroll
            for (int ks = 0; ks < 8; ks++)
                acc[rg][cbi] = __builtin_amdgcn_mfma_f32_16x16x32_bf16(bf1[cbi][ks], a[ks],
                                                                       acc[rg][cbi], 0, 0, 0);
    }

    // prefetch layer-2 B frags (L2 latency hides under barrier + epilogue-1)
    bf16x8 bf2[2][8];
#pragma unroll
    for (int cbi = 0; cbi < 2; cbi++) {
        int cb = 2 * w + cbi;
#pragma unroll
        for (int ks = 0; ks < 8; ks++)
            bf2[cbi][ks] = *(const bf16x8*)(W2 + ((size_t)((ks * 16 + cb) * 64 + l)) * 8);
    }

    __syncthreads();  // all A1 reads done; safe to overwrite H with h

    // ---- epilogue 1: h = relu(acc + b0) -> H column slice [32w, 32w+32) ----
#pragma unroll
    for (int rg = 0; rg < 4; rg++) {
#pragma unroll
        for (int cbi = 0; cbi < 2; cbi++) {
            int colb = (2 * w + cbi) * 16 + q * 4;
            f32x4 bv = *(const f32x4*)(b0 + colb);
            f32x4 v = acc[rg][cbi];
            float v0 = fmaxf(v[0] + bv[0], 0.f);
            float v1 = fmaxf(v[1] + bv[1], 0.f);
            float v2 = fmaxf(v[2] + bv[2], 0.f);
            float v3 = fmaxf(v[3] + bv[3], 0.f);
            u32x2 pk;
            pk[0] = (uint)f2bf(v0) | ((uint)f2bf(v1) << 16);
            pk[1] = (uint)f2bf(v2) | ((uint)f2bf(v3) << 16);
            *(u32x2*)(&H[(size_t)(rg * 16 + r16) * HP + colb]) = pk;
            acc[rg][cbi] = (f32x4){0.f, 0.f, 0.f, 0.f};
        }
    }

    __syncthreads();  // h complete

    // ================= layer 2 =================
#pragma unroll
    for (int rg = 0; rg < 4; rg++) {
        bf16x8 a[8];
        const ushort* hp = &H[(size_t)(rg * 16 + r16) * HP + q * 8];
#pragma unroll
        for (int ks = 0; ks < 8; ks++) a[ks] = *(const bf16x8*)(hp + ks * 32);
#pragma unroll
        for (int cbi = 0; cbi < 2; cbi++)
#pragma unroll
            for (int ks = 0; ks < 8; ks++)
                acc[rg][cbi] = __builtin_amdgcn_mfma_f32_16x16x32_bf16(bf2[cbi][ks], a[ks],
                                                                       acc[rg][cbi], 0, 0, 0);
    }

    // ---- epilogue 2: DIRECT global stores (bf16 both halves) ----
    if (w < 4) {
#pragma unroll
        for (int rg = 0; rg < 4; rg++) {
            int row = row0 + rg * 16 + r16;
#pragma unroll
            for (int cbi = 0; cbi < 2; cbi++) {
                int colb = (2 * w + cbi) * 16 + q * 4;
                f32x4 v = acc[rg][cbi];
                u32x2 pk;
                pk[0] = (uint)f2bf(v[0]) | ((uint)f2bf(v[1]) << 16);
                pk[1] = (uint)f2bf(v[2]) | ((uint)f2bf(v[3]) << 16);
                if (row < n)
                    *(u32x2*)(zb + (size_t)row * 128 + colb) = pk;
            }
        }
    } else {
        int wq = w - 4;
#pragma unroll
        for (int rg = 0; rg < 4; rg++) {
            int row = row0 + rg * 16 + r16;
#pragma unroll
            for (int cbi = 0; cbi < 2; cbi++) {
                int colb = 32 * wq + cbi * 16 + q * 4;
                f32x4 bv = *(const f32x4*)(b1 + colb);
                f32x4 v = acc[rg][cbi];
                v[0] += bv[0]; v[1] += bv[1]; v[2] += bv[2]; v[3] += bv[3];
                u32x2 pk;
                pk[0] = (uint)f2bf(v[0]) | ((uint)f2bf(v[1]) << 16);
                pk[1] = (uint)f2bf(v[2]) | ((uint)f2bf(v[3]) << 16);
                if (row < n)
                    *(u32x2*)(sb + (size_t)row * 128 + colb) = pk;
            }
        }
    }
}

// ---------------- segment mean v4 (validated): uint4 gathers, 16 rows in flight ----------
template <int ADD>
__global__ void segmean_kernel(const u32x4* __restrict__ fp, int rstride,
                               const int* __restrict__ rs, const int* __restrict__ nbr,
                               u32x4* __restrict__ outb, int ostride,
                               float* __restrict__ outf, const ushort* __restrict__ sb, int n) {
    int w = threadIdx.x >> 6;
    int l = threadIdx.x & 63;
    int i = blockIdx.x * 4 + w;
    if (i >= n) return;
    int g = l >> 4, f = l & 15;
    int b = rs[i], e = rs[i + 1];
    float a0 = 0.f, a1 = 0.f, a2 = 0.f, a3 = 0.f, a4 = 0.f, a5 = 0.f, a6 = 0.f, a7 = 0.f;
    auto accum = [&](u32x4 v) {
        a0 += bf2f(v[0] & 0xffffu); a1 += bf2f_hi(v[0]);
        a2 += bf2f(v[1] & 0xffffu); a3 += bf2f_hi(v[1]);
        a4 += bf2f(v[2] & 0xffffu); a5 += bf2f_hi(v[2]);
        a6 += bf2f(v[3] & 0xffffu); a7 += bf2f_hi(v[3]);
    };
    int j = b;
    for (; j + 16 <= e; j += 16) {
        int s0 = nbr[j + g], s1 = nbr[j + 4 + g], s2 = nbr[j + 8 + g], s3 = nbr[j + 12 + g];
        u32x4 v0 = fp[(size_t)s0 * rstride + f];
        u32x4 v1 = fp[(size_t)s1 * rstride + f];
        u32x4 v2 = fp[(size_t)s2 * rstride + f];
        u32x4 v3 = fp[(size_t)s3 * rstride + f];
        accum(v0); accum(v1); accum(v2); accum(v3);
    }
    for (; j + 4 <= e; j += 4) {
        u32x4 v = fp[(size_t)nbr[j + g] * rstride + f];
        accum(v);
    }
    int rem = e - j;
    if (g < rem) {
        u32x4 v = fp[(size_t)nbr[j + g] * rstride + f];
        accum(v);
    }
    a0 += __shfl_xor(a0, 32); a0 += __shfl_xor(a0, 16);
    a1 += __shfl_xor(a1, 32); a1 += __shfl_xor(a1, 16);
    a2 += __shfl_xor(a2, 32); a2 += __shfl_xor(a2, 16);
    a3 += __shfl_xor(a3, 32); a3 += __shfl_xor(a3, 16);
    a4 += __shfl_xor(a4, 32); a4 += __shfl_xor(a4, 16);
    a5 += __shfl_xor(a5, 32); a5 += __shfl_xor(a5, 16);
    a6 += __shfl_xor(a6, 32); a6 += __shfl_xor(a6, 16);
    a7 += __shfl_xor(a7, 32); a7 += __shfl_xor(a7, 16);
    if (g == 0) {
        int dg = e - b;
        float inv = 1.0f / (float)(dg > 1 ? dg : 1);
        a0 *= inv; a1 *= inv; a2 *= inv; a3 *= inv;
        a4 *= inv; a5 *= inv; a6 *= inv; a7 *= inv;
        if (ADD) {
            u32x4 sv = *(const u32x4*)(sb + (size_t)i * 128 + f * 8);
            f32x4 o0, o1;
            o0[0] = bf2f(sv[0] & 0xffffu) + a0; o0[1] = bf2f_hi(sv[0]) + a1;
            o0[2] = bf2f(sv[1] & 0xffffu) + a2; o0[3] = bf2f_hi(sv[1]) + a3;
            o1[0] = bf2f(sv[2] & 0xffffu) + a4; o1[1] = bf2f_hi(sv[2]) + a5;
            o1[2] = bf2f(sv[3] & 0xffffu) + a6; o1[3] = bf2f_hi(sv[3]) + a7;
            float* op = outf + (size_t)i * 128 + f * 8;
            *(f32x4*)op = o0;
            *(f32x4*)(op + 4) = o1;
        } else {
            u32x4 pk;
            pk[0] = (uint)f2bf(a0) | ((uint)f2bf(a1) << 16);
            pk[1] = (uint)f2bf(a2) | ((uint)f2bf(a3) << 16);
            pk[2] = (uint)f2bf(a4) | ((uint)f2bf(a5) << 16);
            pk[3] = (uint)f2bf(a6) | ((uint)f2bf(a7) << 16);
            outb[(size_t)i * ostride + f] = pk;
        }
    }
}

// ---------------- launch ----------------

extern "C" void kernel_launch(void* const* d_in, const int* in_sizes, int n_in,
                              void* d_out, int out_size, void* d_ws, size_t ws_size,
                              hipStream_t stream) {
    const float* x = (const float*)d_in[0];
    const int* ei = (const int*)d_in[1];
    const float* Wl0 = (const float*)d_in[2];
    const float* bl0 = (const float*)d_in[3];
    const float* Wr0 = (const float*)d_in[4];
    const float* Wl1 = (const float*)d_in[5];
    const float* bl1 = (const float*)d_in[6];
    const float* Wr1 = (const float*)d_in[7];
    float* outp = (float*)d_out;

    int n = in_sizes[0] / 128;  // 100000
    int E = in_sizes[1] / 2;    // 1600000
    const int* srcv = ei;
    const int* dstv = ei + E;

    int NB = (n + 255) >> 8;        // 391
    int CE = (E + NBLK - 1) / NBLK; // edges per pA block

    char* w = (char*)d_ws;
    auto align = [](size_t v) { return (v + 255) & ~(size_t)255; };
    size_t off = 0;
    int* rs    = (int*)(w + off); off = align(off + (size_t)(n + 1) * 4);
    int* bcnt  = (int*)(w + off); off = align(off + (size_t)512 * 4);
    int* nbr   = (int*)(w + off); off = align(off + (size_t)E * 4);
    ushort* a1  = (ushort*)(w + off); off = align(off + (size_t)n * 256 * 2);  // [xb | aggb]
    ushort* zb  = (ushort*)(w + off); off = align(off + (size_t)n * 128 * 2);
    ushort* sbf = (ushort*)(w + off); off = align(off + (size_t)n * 128 * 2);  // bf16 self-term
    ushort* w1p = (ushort*)(w + off); off = align(off + (size_t)256 * 256 * 2);
    ushort* w2p = (ushort*)(w + off); off = align(off + (size_t)256 * 256 * 2);
    uint* slab = (uint*)zb;  // slab (9.6 MB) aliases zb (25.6 MB): dead before fused writes zb
    (void)ws_size; (void)n_in; (void)out_size;

    int ncx = (n * 32 + 255) / 256;

    hipMemsetAsync(bcnt, 0, (size_t)512 * 4, stream);

    // CSR build (single edge pass) + conversions
    prep_kernel<<<NBLK + 64 + ncx, 256, 0, stream>>>(x, a1, Wr0, Wl0, w1p, Wl1, Wr1, w2p,
                                                     srcv, dstv, bcnt, slab, E, CE, NB, n);
    p4_kernel<<<NB, 256, 0, stream>>>(slab, bcnt, rs, nbr, n, E, NB);

    int segb = (n + 3) / 4;
    int mb = (n + 63) / 64;
    int ldsz = 64 * HP * 2;  // 33792

    hipFuncSetAttribute((const void*)fused_gemm_kernel,
                        hipFuncAttributeMaxDynamicSharedMemorySize, ldsz);

    // layer 1 gather, fused 2-layer GEMM (BM=64), layer 2 gather + self-term combine
    segmean_kernel<0><<<segb, 256, 0, stream>>>((const u32x4*)a1, 32, rs, nbr,
                                                (u32x4*)a1 + 16, 32, nullptr, nullptr, n);
    fused_gemm_kernel<<<mb, 512, ldsz, stream>>>(a1, w1p, w2p, bl0, bl1, zb, sbf, n);
    segmean_kernel<1><<<segb, 256, 0, stream>>>((const u32x4*)zb, 16, rs, nbr,
                                                nullptr, 0, outp, sbf, n);
}